// Round 5
// baseline (2379.314 us; speedup 1.0000x reference)
//
#include <hip/hip_runtime.h>
#include <stdint.h>

// LSTM cell. B=8192, IN=2048, H=2048.
// R7: (1) rotate fragment reads one phase ahead (phase p reads gate p+1's B
// into alt reg buffer; MFMA consumes buffer read in p-1) -> ds_read latency
// hidden behind a full phase; vmcnt(2) at end of ph3/ph7 makes next side's
// staged data barrier-valid before the ph4/ph8 reads. (2) MFMA shape
// 16x16x32 -> 32x32x16 (2495 vs 2176 TF ubench, half the instructions).
// Gate-interleaved W packing => each 32-col tile is one gate of the same 32
// hidden cols: all 4 gates of an (row,h) land in the same lane/reg index.

#define BQ 8192
#define INF 2048
#define HH 2048
#define KK 4096   // IN + H

typedef __attribute__((ext_vector_type(8))) short short8;
typedef __attribute__((ext_vector_type(8))) unsigned short ushort8;
typedef __attribute__((ext_vector_type(16))) float floatx16;

__device__ __forceinline__ unsigned short f2b(float f) {
    unsigned u = __float_as_uint(f);
    u += 0x7fff + ((u >> 16) & 1);   // round-to-nearest-even
    return (unsigned short)(u >> 16);
}
__device__ __forceinline__ ushort8 cvt8(float4 a, float4 b) {
    ushort8 y;
    y[0] = f2b(a.x); y[1] = f2b(a.y); y[2] = f2b(a.z); y[3] = f2b(a.w);
    y[4] = f2b(b.x); y[5] = f2b(b.y); y[6] = f2b(b.z); y[7] = f2b(b.w);
    return y;
}
__device__ __forceinline__ float fsig(float x) {
    return 1.f / (1.f + __expf(-x));
}
__device__ __forceinline__ float ftanh(float x) {
    return 1.f - 2.f / (__expf(2.f * x) + 1.f);
}

// ---- single pack kernel: [input|h_prev] -> combined bf16 [8192][4096],
//      Wf..Wo -> gate-interleaved bf16 W [8192][4096] (p=(h>>5)*128+g*32+(h&31))
__global__ __launch_bounds__(256) void pack_all(
    const float4* __restrict__ inp, const float4* __restrict__ hp,
    const float4* __restrict__ w0, const float4* __restrict__ w1,
    const float4* __restrict__ w2, const float4* __restrict__ w3,
    unsigned short* __restrict__ comb, unsigned short* __restrict__ wpk)
{
    const int NC16 = BQ * INF / 16;             // 1,048,576 per source
    int v = blockIdx.x * 256 + threadIdx.x;
    if (v < 2 * NC16) {
        int isH = v >= NC16;
        int u16 = v - (isH ? NC16 : 0);
        const float4* src = isH ? hp : inp;
        float4 x0 = src[u16 * 4];
        float4 x1 = src[u16 * 4 + 1];
        float4 x2 = src[u16 * 4 + 2];
        float4 x3 = src[u16 * 4 + 3];
        int u = u16 * 16;
        int b = u >> 11;
        int k = u & 2047;
        unsigned short* d = comb + (size_t)b * KK + k + (isH ? INF : 0);
        *(ushort8*)d       = cvt8(x0, x1);
        *(ushort8*)(d + 8) = cvt8(x2, x3);
    } else {
        int w = v - 2 * NC16;
        size_t e = (size_t)w * 16;
        int g = (int)(e >> 23);
        int u = (int)(e & ((1u << 23) - 1));
        int h = u >> 12;
        int k = u & 4095;
        const float4* src = (g == 0) ? w0 : (g == 1) ? w1 : (g == 2) ? w2 : w3;
        float4 x0 = src[(u >> 2)];
        float4 x1 = src[(u >> 2) + 1];
        float4 x2 = src[(u >> 2) + 2];
        float4 x3 = src[(u >> 2) + 3];
        int p = ((h >> 5) << 7) + (g << 5) + (h & 31);
        unsigned short* d = wpk + (size_t)p * KK + k;
        *(ushort8*)d       = cvt8(x0, x1);
        *(ushort8*)(d + 8) = cvt8(x2, x3);
    }
}

// ---- fused 256x256 8-phase GEMM (32x32x16 MFMA, rotated reads) + LSTM ----
// 512 threads = 8 waves, wave grid 4(M) x 2(N): per-wave 64 rows x 128 cols
// = 2 row-tiles x 4 gate-tiles of 32x32.
// LDS 128 KiB: s0/s1 x [A-lo|A-hi|B-lo|B-hi] @ 16 KiB, XOR-swizzled 16B chunks.
__global__ __launch_bounds__(512, 2) void lstm_fused(
    const unsigned short* __restrict__ A,   // combined bf16 [8192][4096]
    const unsigned short* __restrict__ W,   // packed bf16 [8192][4096]
    const float* __restrict__ cprev,
    const float* __restrict__ bf_, const float* __restrict__ bi_,
    const float* __restrict__ bg_, const float* __restrict__ bo_,
    float* __restrict__ out)
{
    __shared__ unsigned short lds[65536];   // 128 KiB
    char* ldsb = (char*)lds;

    const int t    = threadIdx.x;
    const int wv   = t >> 6;
    const int lane = t & 63;
    const int wm   = wv >> 1;      // 0..3 -> row base wm*64
    const int wn   = wv & 1;       // 0..1 -> col base wn*128
    const int lq   = lane & 31;    // row/col within 32-tile
    const int lh   = lane >> 5;    // k-granule select
    const int x7   = lq & 7;

    // bijective XCD swizzle (1024 wgs, 1024%8==0)
    int lin = blockIdx.y * 32 + blockIdx.x;
    lin = (lin & 7) * 128 + (lin >> 3);
    const int m0 = (lin >> 5) << 8;        // batch tile base (256 rows)
    const int n0 = (lin & 31) << 8;        // packed-row tile base (256)

    // staging source: lane covers row (wv*16 + lane>>3), swizzled k-chunk
    const int koff = ((lane & 7) ^ (lane >> 3)) << 3;   // elements
    const unsigned short* aR = A + (size_t)(m0 + wv * 16 + (lane >> 3)) * KK + koff;
    const unsigned short* bR = W + (size_t)(n0 + wv * 16 + (lane >> 3)) * KK + koff;
    const int stgOff = wv * 16 * 128;      // LDS byte offset of wave's 16 rows

    // fragment-read bases (byte offsets). Row within 128-row region is a
    // multiple-of-8 base + lq, so the swizzle xor operand is just lq&7.
    const int aRow = (wm >> 1) * 16384 + (((wm & 1) * 64 + lq) * 128);
    const int bRow = 32768 + wn * 16384 + lq * 128;
    int gOff[4];
#pragma unroll
    for (int ks = 0; ks < 4; ++ks) gOff[ks] = ((2 * ks + lh) ^ x7) << 4;

    floatx16 acc[2][4];   // [row-tile i][gate]
#pragma unroll
    for (int i = 0; i < 2; ++i)
#pragma unroll
        for (int g = 0; g < 4; ++g) acc[i][g] = (floatx16)0.f;

    short8 aF[2][4];          // current side's A: [i][ks]
    short8 bbA[4], bbB[4];    // double-buffered B gate fragments [ks]

#define STAGE(srcbase, ldsoff, kk)                                              \
    do {                                                                        \
        __builtin_amdgcn_global_load_lds(                                       \
            (const __attribute__((address_space(1))) void*)((srcbase) + (kk)),  \
            (__attribute__((address_space(3))) void*)(ldsb + (ldsoff) + stgOff),\
            16, 0, 0);                                                          \
        __builtin_amdgcn_global_load_lds(                                       \
            (const __attribute__((address_space(1))) void*)((srcbase) + 8 * KK + (kk)), \
            (__attribute__((address_space(3))) void*)(ldsb + (ldsoff) + stgOff + 1024), \
            16, 0, 0);                                                          \
    } while (0)

    auto LDAall = [&](int side) {
#pragma unroll
        for (int i = 0; i < 2; ++i)
#pragma unroll
            for (int ks = 0; ks < 4; ++ks)
                aF[i][ks] = *(const short8*)(ldsb + side * 65536 + aRow + i * 4096 + gOff[ks]);
    };
    auto LDB = [&](int side, int g, short8* d) {
#pragma unroll
        for (int ks = 0; ks < 4; ++ks)
            d[ks] = *(const short8*)(ldsb + side * 65536 + bRow + g * 4096 + gOff[ks]);
    };

#define BAR()  __builtin_amdgcn_s_barrier()
#define SB0()  __builtin_amdgcn_sched_barrier(0)
#define VM2()  do { asm volatile("s_waitcnt vmcnt(2)" ::: "memory"); SB0(); } while (0)
#define VM4()  do { asm volatile("s_waitcnt vmcnt(4)" ::: "memory"); SB0(); } while (0)

    // MFMA cluster: gate g, B-buffer Bb. 8 x 32x32x16, 2 indep acc chains.
#define CL(g, Bb)                                                              \
    do {                                                                       \
        __builtin_amdgcn_s_setprio(1);                                         \
        _Pragma("unroll")                                                      \
        for (int ks = 0; ks < 4; ++ks) {                                       \
            acc[0][g] = __builtin_amdgcn_mfma_f32_32x32x16_bf16(               \
                aF[0][ks], Bb[ks], acc[0][g], 0, 0, 0);                        \
            acc[1][g] = __builtin_amdgcn_mfma_f32_32x32x16_bf16(               \
                aF[1][ks], Bb[ks], acc[1][g], 0, 0, 0);                        \
        }                                                                      \
        __builtin_amdgcn_s_setprio(0);                                         \
    } while (0)

    // prologue: tile0 (s0) A+B, tile1 (s1) A; then prime aF + bbA(g0,s0)
    STAGE(aR, 0, 0);
    STAGE(aR + 128 * KK, 16384, 0);
    STAGE(bR, 32768, 0);
    STAGE(bR + 128 * KK, 49152, 0);
    STAGE(aR, 65536, 64);
    STAGE(aR + 128 * KK, 81920, 64);
    VM4();   // tile0 A+B landed; tile1-A may be in flight
    BAR();
    SB0();
    LDAall(0);
    LDB(0, 0, bbA);

#pragma unroll 1
    for (int it = 0; it < 32; ++it) {
        const int k1 = ((2 * it + 1) & 63) << 6;
        const int k2 = ((2 * it + 2) & 63) << 6;
        const int k3 = ((2 * it + 3) & 63) << 6;

        // ph1: MFMA g0(s0)[bbA]; read g1(s0)->bbB; stage B-lo(u+1)->s1
        LDB(0, 1, bbB);
        STAGE(bR, 98304, k1);
        SB0();
        CL(0, bbA);
        BAR();

        // ph2: MFMA g1(s0)[bbB]; read g2(s0)->bbA; stage B-hi(u+1)->s1
        LDB(0, 2, bbA);
        STAGE(bR + 128 * KK, 114688, k1);
        SB0();
        CL(1, bbB);
        BAR();

        // ph3: MFMA g2(s0)[bbA]; read g3(s0)->bbB; stage A-lo(u+2)->s0;
        //      vmcnt(2): forces A(u+1)+B(u+1) complete (leaves ph3's stage)
        LDB(0, 3, bbB);
        STAGE(aR, 0, k2);
        SB0();
        CL(2, bbA);
        VM2();
        BAR();
        SB0();

        // ph4: MFMA g3(s0)[bbB]; read g0(s1)->bbA; after cluster read s1-A;
        //      stage A-hi(u+2)->s0
        LDB(1, 0, bbA);
        STAGE(aR + 128 * KK, 16384, k2);
        SB0();
        CL(3, bbB);
        LDAall(1);
        BAR();

        // ph5: MFMA g0(s1)[bbA]; read g1(s1)->bbB; stage B-lo(u+2)->s0
        LDB(1, 1, bbB);
        STAGE(bR, 32768, k2);
        SB0();
        CL(0, bbA);
        BAR();

        // ph6: MFMA g1(s1)[bbB]; read g2(s1)->bbA; stage B-hi(u+2)->s0
        LDB(1, 2, bbA);
        STAGE(bR + 128 * KK, 49152, k2);
        SB0();
        CL(1, bbB);
        BAR();

        // ph7: MFMA g2(s1)[bbA]; read g3(s1)->bbB; stage A-lo(u+3)->s1;
        //      vmcnt(2): forces A(u+2)+B(u+2) complete (leaves ph7's stage)
        LDB(1, 3, bbB);
        STAGE(aR, 65536, k3);
        SB0();
        CL(2, bbA);
        VM2();
        BAR();
        SB0();

        // ph8: MFMA g3(s1)[bbB]; read g0(s0,u+2)->bbA; after cluster read
        //      s0-A(u+2); stage A-hi(u+3)->s1
        LDB(0, 0, bbA);
        STAGE(aR + 128 * KK, 81920, k3);
        SB0();
        CL(3, bbB);
        LDAall(0);
        BAR();
    }

    // ---- in-register LSTM epilogue (32x32 C layout) ----
    // acc[i][g][reg]: row = m0 + wm*64 + i*32 + (reg&3) + 8*(reg>>2) + 4*lh
    //                 hidden col h = (n0>>2) + wn*32 + lq  (same for all g)
    const int h = (n0 >> 2) + wn * 32 + lq;
    const float bFv = bf_[h], bIv = bi_[h], bGv = bg_[h], bOv = bo_[h];
    const int rowb = m0 + wm * 64 + 4 * lh;
#pragma unroll
    for (int i = 0; i < 2; ++i) {
#pragma unroll
        for (int reg = 0; reg < 16; ++reg) {
            int row = rowb + i * 32 + (reg & 3) + 8 * (reg >> 2);
            size_t gi = (size_t)row * HH + h;
            float xf = acc[i][0][reg] + bFv;
            float xi = acc[i][1][reg] + bIv;
            float xg = acc[i][2][reg] + bGv;
            float xo = acc[i][3][reg] + bOv;
            float f  = fsig(xf);
            float ii = fsig(xi);
            float g  = ftanh(xg);
            float o  = fsig(xo);
            float c  = f * cprev[gi] + ii * g;
            float hv = o * ftanh(c);
            out[gi] = hv;
            out[(size_t)BQ * HH + gi] = c;
        }
    }
}

extern "C" void kernel_launch(void* const* d_in, const int* in_sizes, int n_in,
                              void* d_out, int out_size, void* d_ws, size_t ws_size,
                              hipStream_t stream) {
    const float* input  = (const float*)d_in[0];
    const float* h_prev = (const float*)d_in[1];
    const float* c_prev = (const float*)d_in[2];
    const float* Wf = (const float*)d_in[3];
    const float* bf_ = (const float*)d_in[4];
    const float* Wi = (const float*)d_in[5];
    const float* bi_ = (const float*)d_in[6];
    const float* Wg = (const float*)d_in[7];
    const float* bg_ = (const float*)d_in[8];
    const float* Wo = (const float*)d_in[9];
    const float* bo_ = (const float*)d_in[10];
    float* out = (float*)d_out;

    unsigned short* combined = (unsigned short*)d_ws;                   // 64 MB
    unsigned short* Wpk = (unsigned short*)d_ws + (size_t)BQ * KK;      // 64 MB

    pack_all<<<dim3(16384), 256, 0, stream>>>(
        (const float4*)input, (const float4*)h_prev,
        (const float4*)Wf, (const float4*)Wi, (const float4*)Wg, (const float4*)Wo,
        combined, Wpk);
    lstm_fused<<<dim3(32, 32), 512, 0, stream>>>(
        combined, Wpk, c_prev, bf_, bi_, bg_, bo_, out);
}